// Round 15
// baseline (87.308 us; speedup 1.0000x reference)
//
#include <hip/hip_runtime.h>

#define FDIM  256
#define H1D   256
#define H2D   128
#define BATCH 4096
#define NPART 32

typedef _Float16 half8 __attribute__((ext_vector_type(8)));
typedef float    f32x4 __attribute__((ext_vector_type(4)));

#define W2F_HALVES  ((size_t)FDIM * H1D * H2D)   // 8388608  (16.78 MB)
#define XH_HALVES   ((size_t)FDIM * BATCH)       // 1048576  (2 MB)
#define W1B1_HALVES ((size_t)FDIM * 8 * 4 * 16)  // 131072   (0.25 MB)

union H8U {
    half8 v;
    unsigned u[4];
};

// ---------------------------------------------------------------------------
// prep_all (identical to round-10/14 version):
//  [0,2048):   W2 -> w2f f16 B-fragments, k-perm kpat(g,j)=4g+j / 16+4g+(j-4)
//  [2048,2304): x (B,F) f32 -> xh (F,B) f16 transpose via LDS tile
//  [2304,2336): W1,b1 -> w1b1 packed per (f,s,g), SAME kpat sigma as w2f.
// ---------------------------------------------------------------------------
__global__ __launch_bounds__(256) void prep_all(
    const float* __restrict__ x,  const float* __restrict__ W1,
    const float* __restrict__ b1, const float* __restrict__ W2,
    _Float16* __restrict__ w2f, _Float16* __restrict__ xh,
    _Float16* __restrict__ w1b1) {
    __shared__ _Float16 tile[64][66];
    const int tid = threadIdx.x;
    const int bid = blockIdx.x;
    if (bid < 2048) {
        const int f = bid >> 3, s = bid & 7;
        const int lane = tid & 63, g = lane >> 4, ln = lane & 15;
        const int w = tid >> 6;
#pragma unroll
        for (int h = 0; h < 2; ++h) {
            const int tq = w * 2 + h;
            half8 v;
#pragma unroll
            for (int j = 0; j < 8; ++j) {
                const int k = s * 32 + 4 * g + (j < 4 ? j : 12 + j);
                v[j] = (_Float16)W2[(size_t)(f * H1D + k) * H2D + tq * 16 + ln];
            }
            *(half8*)(w2f + (((size_t)(f * 8 + s) * 8 + tq) * 64 + lane) * 8) = v;
        }
    } else if (bid < 2304) {
        const int idx = bid - 2048;
        const int bt = idx >> 2, ft = idx & 3;
        const int tr = tid >> 2;
        const int c0 = (tid & 3) * 16;
#pragma unroll
        for (int j = 0; j < 4; ++j) {
            const float4 v = *(const float4*)(
                x + (size_t)(bt * 64 + tr) * FDIM + ft * 64 + c0 + j * 4);
            tile[tr][c0 + j * 4 + 0] = (_Float16)v.x;
            tile[tr][c0 + j * 4 + 1] = (_Float16)v.y;
            tile[tr][c0 + j * 4 + 2] = (_Float16)v.z;
            tile[tr][c0 + j * 4 + 3] = (_Float16)v.w;
        }
        __syncthreads();
        const int fr = tid >> 2;
        const int bb = (tid & 3) * 16;
        half8 o0, o1;
#pragma unroll
        for (int i = 0; i < 8; ++i) o0[i] = tile[bb + i][fr];
#pragma unroll
        for (int i = 0; i < 8; ++i) o1[i] = tile[bb + 8 + i][fr];
        _Float16* dst = xh + (size_t)(ft * 64 + fr) * BATCH + bt * 64 + bb;
        *(half8*)dst = o0;
        *(half8*)(dst + 8) = o1;
    } else {
        const int idx = (bid - 2304) * 256 + tid;
        const int f = idx >> 5, s = (idx >> 2) & 7, g = idx & 3;
        const float4 wlo = *(const float4*)(W1 + f * H1D + s * 32 + 4 * g);
        const float4 whi = *(const float4*)(W1 + f * H1D + s * 32 + 16 + 4 * g);
        const float4 blo = *(const float4*)(b1 + f * H1D + s * 32 + 4 * g);
        const float4 bhi = *(const float4*)(b1 + f * H1D + s * 32 + 16 + 4 * g);
        half8 wv, bv;
        wv[0] = (_Float16)wlo.x; wv[1] = (_Float16)wlo.y;
        wv[2] = (_Float16)wlo.z; wv[3] = (_Float16)wlo.w;
        wv[4] = (_Float16)whi.x; wv[5] = (_Float16)whi.y;
        wv[6] = (_Float16)whi.z; wv[7] = (_Float16)whi.w;
        bv[0] = (_Float16)blo.x; bv[1] = (_Float16)blo.y;
        bv[2] = (_Float16)blo.z; bv[3] = (_Float16)blo.w;
        bv[4] = (_Float16)bhi.x; bv[5] = (_Float16)bhi.y;
        bv[6] = (_Float16)bhi.z; bv[7] = (_Float16)bhi.w;
        _Float16* dst = w1b1 + (size_t)((f * 8 + s) * 4 + g) * 16;
        *(half8*)dst = wv;
        *(half8*)(dst + 8) = bv;
    }
}

// ---------------------------------------------------------------------------
// Main (round-14 structure + VALU diet):
// 512 blocks (2/CU) x 4 waves (2/SIMD); waves share (fsplit, ns). Per
// feature: stage next feature's 32 KB B-slice into LDS (global_load_lds,
// issued at feature start, 1 barrier/feature); chunks read B-frags via LDS
// ring. A-frag recompute now via INLINE-ASM v_pk_fma_f16 + v_pk_max_f16
// (guaranteed packed; measured VALU count showed clang scalarized the
// half8 form), all 4 af hoisted BEFORE a clean 16-MFMA burst. Epilogue on
// float2 (v_pk_* eligible). b2 folded into acc init.
// ---------------------------------------------------------------------------
__global__ __launch_bounds__(256, 2) void coxnam_main(
    const _Float16* __restrict__ xh,  const _Float16* __restrict__ w1b1,
    const _Float16* __restrict__ w2f, const float* __restrict__ b2,
    const float* __restrict__ W3,     float* __restrict__ partial) {
    __shared__ _Float16 lsh[2][16384];   // 2 x 32 KB feature B-slices

    const int t    = threadIdx.x;
    const int w    = t >> 6;
    const int lane = t & 63;
    const int g = lane >> 4, ln = lane & 15;
    const int bid = blockIdx.x;                 // 0..511
    const int xcd = bid & 7;
    const int r_  = bid >> 3;                   // 0..63
    const int fsplit = (xcd << 1) | (r_ & 1);   // 0..15 (16 features each)
    const int u   = r_ >> 1;                    // 0..31
    const int ns  = u & 1, btg = u >> 1;        // btg 0..15
    const int b0  = (btg * 4 + w) * 64;         // 64 rows per wave
    const int n0  = ns * 64, f0 = fsplit * 16;

    auto stage = [&](int f, int buf) {
        const _Float16* src = w2f + (size_t)f * 32768 + ns * 2048 + t * 8;
#pragma unroll
        for (int i = 0; i < 8; ++i) {
            __builtin_amdgcn_global_load_lds(
                (const __attribute__((address_space(1))) unsigned int*)
                    (const void*)(src + i * 4096),
                (__attribute__((address_space(3))) unsigned int*)
                    (void*)&lsh[buf][i * 2048 + w * 512],
                16, 0, 0);
        }
    };

    f32x4 acc[4][4];
    float sacc[4][4];
    half8 bfb[2][4];
    H8U wvb[2], bvb[2];
    unsigned xsp[4];                 // half2 splats of x
    const unsigned zero2 = 0;        // packed f16 zero pair (reg for asm)
#pragma unroll
    for (int mi = 0; mi < 4; ++mi)
#pragma unroll
        for (int r = 0; r < 4; ++r) sacc[mi][r] = 0.f;

    int off_w = f0 * 512 + g * 16;              // w1b1: +64 per chunk
    int off_x = f0 * BATCH + b0 + ln;           // xh:   +BATCH per feature
    int off_e = f0 * H2D + n0 + ln;             // b2/W3:+H2D per feature

    stage(f0, 0);
    wvb[0].v = *(const half8*)(w1b1 + off_w);
    bvb[0].v = *(const half8*)(w1b1 + off_w + 8);
    off_w += 64;
    __syncthreads();

    const unsigned short* xbits = (const unsigned short*)xh;

    for (int fi = 0; fi < 16; ++fi) {
        const int buf = fi & 1;
        {
            float b2v[4];
#pragma unroll
            for (int nt = 0; nt < 4; ++nt) b2v[nt] = b2[off_e + nt * 16];
#pragma unroll
            for (int mi = 0; mi < 4; ++mi)
#pragma unroll
                for (int nt = 0; nt < 4; ++nt)
                    acc[mi][nt] = (f32x4){b2v[nt], b2v[nt], b2v[nt], b2v[nt]};
        }
#pragma unroll
        for (int mi = 0; mi < 4; ++mi) {
            const unsigned us = xbits[off_x + mi * 16];
            xsp[mi] = us | (us << 16);
        }
        const _Float16* lbase = &lsh[buf][0] + lane * 8;
#pragma unroll
        for (int nt = 0; nt < 4; ++nt)
            bfb[0][nt] = *(const half8*)(lbase + nt * 512);
        if (fi < 15) stage(f0 + fi + 1, buf ^ 1);

#pragma unroll
        for (int s = 0; s < 8; ++s) {
            const int cur = s & 1, nxt = cur ^ 1;   // compile-time
            if (s < 7) {
#pragma unroll
                for (int nt = 0; nt < 4; ++nt)
                    bfb[nxt][nt] =
                        *(const half8*)(lbase + (s + 1) * 2048 + nt * 512);
            }
            wvb[nxt].v = *(const half8*)(w1b1 + off_w);
            bvb[nxt].v = *(const half8*)(w1b1 + off_w + 8);
            off_w += 64;
            // ---- A-frag recompute: guaranteed-packed f16, hoisted ----
            H8U af[4];
#pragma unroll
            for (int mi = 0; mi < 4; ++mi)
#pragma unroll
                for (int q = 0; q < 4; ++q) {
                    unsigned d;
                    asm("v_pk_fma_f16 %0, %1, %2, %3"
                        : "=v"(d)
                        : "v"(xsp[mi]), "v"(wvb[cur].u[q]), "v"(bvb[cur].u[q]));
                    asm("v_pk_max_f16 %0, %1, %2"
                        : "=v"(af[mi].u[q])
                        : "v"(d), "v"(zero2));
                }
            // ---- clean 16-MFMA burst ----
            __builtin_amdgcn_s_setprio(1);
#pragma unroll
            for (int mi = 0; mi < 4; ++mi)
#pragma unroll
                for (int nt = 0; nt < 4; ++nt)
                    acc[mi][nt] = __builtin_amdgcn_mfma_f32_16x16x32_f16(
                        af[mi].v, bfb[cur][nt], acc[mi][nt], 0, 0, 0);
            __builtin_amdgcn_s_setprio(0);
        }
        // ---- epilogue: relu(acc) . W3 -> sacc, on float2 (pk-eligible) ----
        {
            typedef float f32x2 __attribute__((ext_vector_type(2)));
            float w3v[4];
#pragma unroll
            for (int nt = 0; nt < 4; ++nt) w3v[nt] = W3[off_e + nt * 16];
#pragma unroll
            for (int mi = 0; mi < 4; ++mi) {
                f32x2* sp = (f32x2*)&sacc[mi][0];
#pragma unroll
                for (int nt = 0; nt < 4; ++nt) {
                    const f32x2* ap = (const f32x2*)&acc[mi][nt];
                    const f32x2 w3s = {w3v[nt], w3v[nt]};
                    const f32x2 zz = {0.f, 0.f};
#pragma unroll
                    for (int h = 0; h < 2; ++h)
                        sp[h] += __builtin_elementwise_max(ap[h], zz) * w3s;
                }
            }
        }
        off_x += BATCH;
        off_e += H2D;
        __syncthreads();   // next feature's stage complete; buf swap safe
    }

    // ---- reduce over the 16 n-lanes ----
#pragma unroll
    for (int mi = 0; mi < 4; ++mi)
#pragma unroll
        for (int r = 0; r < 4; ++r) {
            float v = sacc[mi][r];
            v += __shfl_xor(v, 1, 16);
            v += __shfl_xor(v, 2, 16);
            v += __shfl_xor(v, 4, 16);
            v += __shfl_xor(v, 8, 16);
            sacc[mi][r] = v;
        }
    if (ln == 0) {
        float* dst = partial + (size_t)(fsplit * 2 + ns) * BATCH + b0;
#pragma unroll
        for (int mi = 0; mi < 4; ++mi) {
            f32x4 o = {sacc[mi][0], sacc[mi][1], sacc[mi][2], sacc[mi][3]};
            *(f32x4*)(dst + mi * 16 + g * 4) = o;
        }
    }
}

// ---------------------------------------------------------------------------
// Final reduction over 32 partials + sum of b3.
// ---------------------------------------------------------------------------
__global__ __launch_bounds__(256) void reduce_out(const float* __restrict__ partial,
                                                  const float* __restrict__ b3,
                                                  float* __restrict__ out) {
    const int b = blockIdx.x * 256 + threadIdx.x;
    float v = 0.f;
#pragma unroll
    for (int p = 0; p < NPART; ++p) v += partial[(size_t)p * BATCH + b];
    float sb3 = 0.f;
#pragma unroll 4
    for (int f4 = 0; f4 < FDIM; f4 += 4) {
        const float4 t = *(const float4*)(b3 + f4);
        sb3 += t.x + t.y + t.z + t.w;
    }
    out[b] = v + sb3;
}

extern "C" void kernel_launch(void* const* d_in, const int* in_sizes, int n_in,
                              void* d_out, int out_size, void* d_ws, size_t ws_size,
                              hipStream_t stream) {
    const float* x  = (const float*)d_in[0];
    const float* W1 = (const float*)d_in[1];
    const float* b1 = (const float*)d_in[2];
    const float* W2 = (const float*)d_in[3];
    const float* b2 = (const float*)d_in[4];
    const float* W3 = (const float*)d_in[5];
    const float* b3 = (const float*)d_in[6];

    _Float16* w2f  = (_Float16*)d_ws;
    _Float16* xh   = w2f + W2F_HALVES;
    _Float16* w1b1 = xh + XH_HALVES;
    float* partial = (float*)(w1b1 + W1B1_HALVES);
    const size_t need = (W2F_HALVES + XH_HALVES + W1B1_HALVES) * sizeof(_Float16) +
                        (size_t)NPART * BATCH * sizeof(float);
    if (ws_size < need) return;  // insufficient scratch; fail visibly

    prep_all<<<2336, 256, 0, stream>>>(x, W1, b1, W2, w2f, xh, w1b1);
    coxnam_main<<<512, 256, 0, stream>>>(xh, w1b1, w2f, b2, W3, partial);
    reduce_out<<<BATCH / 256, 256, 0, stream>>>(partial, b3, (float*)d_out);
}